// Round 4
// baseline (7009.110 us; speedup 1.0000x reference)
//
#include <hip/hip_runtime.h>
#include <string.h>

// LSTM_13159779795583 : 2-layer LSTM (B=32,T=512,IN=256,H=1024) + FC(1024->256)
//
// Round 4: NO grid barrier — per-wave dataflow synchronization.
//  - h layout [step][wg][batch][8units]: producer chunk = 512B contiguous
//    (coalesced 8B/lane WT stores), consumer A-loads 512B-contiguous/32 lanes.
//  - per-(wg,layer) monotone step-counter flags (dense u32[128]); each wave
//    polls ONLY its 64 producers with one coalesced load; WGs drift freely
//    (h slots are write-once -> no WAR).
//  - cell phase on light waves 2 (L0) and 7 (L1) whose own MFMA input is x
//    (flag-free), so flag publication is never behind heavy-wave work.
//  - one __syncthreads per step; stage[] double-buffered in LDS.
//  - producer protocol: WT h stores -> s_waitcnt(0) -> relaxed flag store.

#define T_STEPS 512
#define BATCH   32
#define IN_DIM  256
#define HID     1024
#define OUT_DIM 256
#define NWG     128
#define TPB     512
#define UNITS   8              // hidden units per WG per layer
#define CH      (BATCH * UNITS) // fp16 per h-chunk (256 = 512B)

typedef _Float16 half8  __attribute__((ext_vector_type(8)));
typedef float    f32x16 __attribute__((ext_vector_type(16)));

__device__ __forceinline__ float sigm(float x)      { return 1.f / (1.f + __expf(-x)); }
__device__ __forceinline__ float tanh_fast(float x) { return 2.f / (1.f + __expf(-2.f * x)) - 1.f; }

#define ATOMIC_ST(p, v)  __hip_atomic_store((p), (v), __ATOMIC_RELAXED, __HIP_MEMORY_SCOPE_AGENT)
#define ATOMIC_ST8(p, v) __hip_atomic_store((p), (v), __ATOMIC_RELAXED, __HIP_MEMORY_SCOPE_AGENT)
#define ATOMIC_LD(p)     __hip_atomic_load((p), __ATOMIC_RELAXED, __HIP_MEMORY_SCOPE_AGENT)

__global__ __launch_bounds__(TPB, 2) void lstm_persist(
    const float* __restrict__ W_ih0, const float* __restrict__ W_hh0,
    const float* __restrict__ b_ih0, const float* __restrict__ b_hh0,
    const float* __restrict__ W_ih1, const float* __restrict__ W_hh1,
    const float* __restrict__ b_ih1, const float* __restrict__ b_hh1,
    const _Float16* __restrict__ xb,
    _Float16* __restrict__ h0a, _Float16* __restrict__ h1a,
    unsigned* __restrict__ flags0, unsigned* __restrict__ flags1)
{
    __shared__ float stage[2][8][BATCH][33];  // double-buffered, padded
    __shared__ float cst[2][BATCH][UNITS];    // cell state, both layers
    __shared__ float biasS[2][32];            // b_ih + b_hh, this WG's rows

    const int tid  = threadIdx.x;
    const int w    = tid >> 6;        // wave id 0..7
    const int lane = tid & 63;
    const int rho  = lane & 31;       // MFMA A m-row (batch)
    const int kg   = (lane >> 5) << 3;// k sub-offset (0 or 8)
    const int blk  = blockIdx.x;

    // wave roles: matrix 0=W_hh0 1=W_ih0 2=W_ih1 3=W_hh1 ; K-range split
    const int matv[8]   = {0, 0,   1, 2, 2,   3, 3,   1};
    const int kbasev[8] = {0, 512, 0, 0, 512, 0, 512, 128};
    const int nkv[8]    = {32, 32, 8, 32, 32, 32, 32, 8};
    const int mat   = matv[w];
    const int kbase = kbasev[w];
    const int nk    = nkv[w];
    const int layer = (mat >= 2) ? 1 : 0;

    const float* wptr; int rowlen;
    if      (mat == 0) { wptr = W_hh0; rowlen = HID;    }
    else if (mat == 1) { wptr = W_ih0; rowlen = IN_DIM; }
    else if (mat == 2) { wptr = W_ih1; rowlen = HID;    }
    else               { wptr = W_hh1; rowlen = HID;    }

    // this lane's weight row: gate = rho>>3, unit = blk*8 + (rho&7)
    const int grow = (rho >> 3) * HID + blk * UNITS + (rho & 7);

    // ---- load + pack B fragments into registers (fp32 -> fp16), once ----
    half8 B[32];
    #pragma unroll
    for (int kk = 0; kk < 32; ++kk) {
        half8 bf;
        if (kk < nk) {
            const float* p = wptr + (size_t)grow * rowlen + kbase + kk * 16 + kg;
            float4 lo = *(const float4*)p;
            float4 hi = *(const float4*)(p + 4);
            bf[0] = (_Float16)lo.x; bf[1] = (_Float16)lo.y;
            bf[2] = (_Float16)lo.z; bf[3] = (_Float16)lo.w;
            bf[4] = (_Float16)hi.x; bf[5] = (_Float16)hi.y;
            bf[6] = (_Float16)hi.z; bf[7] = (_Float16)hi.w;
        } else {
            #pragma unroll
            for (int j = 0; j < 8; ++j) bf[j] = (_Float16)0.f;
        }
        B[kk] = bf;
    }

    // ---- init: biases, cell state ----
    if (tid < 64) {
        int L = tid >> 5, n = tid & 31;
        int gr = (n >> 3) * HID + blk * UNITS + (n & 7);
        biasS[L][n] = L ? (b_ih1[gr] + b_hh1[gr]) : (b_ih0[gr] + b_hh0[gr]);
    }
    ((float*)cst)[tid] = 0.f;  // 512 floats, one per thread
    __syncthreads();
    // (flags + h slot-0 zeroed by host-side memsets, stream-ordered)

    // ---- cell helper: one wave handles one layer (4 units/lane) ----
    auto docell = [&](int L, int sb, _Float16* dst, unsigned* flag, unsigned val) {
        const int b  = lane >> 1;
        const int u0 = (lane & 1) * 4;
        _Float16 hh[4];
        #pragma unroll
        for (int j = 0; j < 4; ++j) {
            const int u = u0 + j;
            float pre[4];
            #pragma unroll
            for (int g = 0; g < 4; ++g) {
                const int n = g * 8 + u;
                float v = biasS[L][n];
                if (L == 0)
                    v += stage[sb][0][b][n] + stage[sb][1][b][n]
                       + stage[sb][2][b][n] + stage[sb][7][b][n];
                else
                    v += stage[sb][3][b][n] + stage[sb][4][b][n]
                       + stage[sb][5][b][n] + stage[sb][6][b][n];
                pre[g] = v;
            }
            float iv = sigm(pre[0]);
            float fv = sigm(pre[1]);
            float gv = tanh_fast(pre[2]);
            float ov = sigm(pre[3]);
            float c  = fv * cst[L][b][u] + iv * gv;
            cst[L][b][u] = c;
            hh[j] = (_Float16)(ov * tanh_fast(c));
        }
        unsigned long long pk;
        memcpy(&pk, hh, 8);
        ATOMIC_ST8((unsigned long long*)(dst + b * UNITS + u0), pk);
        __atomic_signal_fence(__ATOMIC_SEQ_CST);
        __builtin_amdgcn_s_waitcnt(0);            // all h stores acked
        __atomic_signal_fence(__ATOMIC_SEQ_CST);
        if (lane == 0) ATOMIC_ST(flag, val);      // publish
    };

    // ---- main loop: step s = layer0@t=s and layer1@t=s-1, no grid barrier ----
    for (int s = 0; s <= T_STEPS; ++s) {
        const int  sb  = s & 1;
        const bool act = (layer == 0) ? (s < T_STEPS) : (s >= 1);
        if (act) {
            // poll ONLY this wave's 64 producers (x-consumers poll nothing)
            if (mat != 1) {
                const unsigned* fp   = (mat == 3) ? flags1 : flags0;
                const unsigned  need = (mat == 3) ? (unsigned)(s - 1) : (unsigned)s;
                const int pb = kbase >> 3;
                unsigned v = ATOMIC_LD(&fp[pb + lane]);
                while (!__all(v >= need)) {
                    __builtin_amdgcn_s_sleep(1);
                    v = ATOMIC_LD(&fp[pb + lane]);
                }
            }
            const _Float16* src;
            const int cbase = (kbase >> 3) + (kg >> 3);
            if      (mat == 1) src = xb  + ((size_t)s * 32 + cbase) * CH;
            else if (mat == 3) src = h1a + ((size_t)(s - 1) * NWG + cbase) * CH;
            else               src = h0a + ((size_t)s * NWG + cbase) * CH;
            const _Float16* ap = src + rho * UNITS;

            f32x16 acc0, acc1;
            #pragma unroll
            for (int r = 0; r < 16; ++r) { acc0[r] = 0.f; acc1[r] = 0.f; }
            #pragma unroll
            for (int kk = 0; kk < 32; kk += 2) {
                if (kk < nk) {
                    half8 a = *(const half8*)(ap + (size_t)kk * 2 * CH);
                    acc0 = __builtin_amdgcn_mfma_f32_32x32x16_f16(a, B[kk], acc0, 0, 0, 0);
                }
                if (kk + 1 < nk) {
                    half8 a = *(const half8*)(ap + (size_t)(kk + 1) * 2 * CH);
                    acc1 = __builtin_amdgcn_mfma_f32_32x32x16_f16(a, B[kk + 1], acc1, 0, 0, 0);
                }
            }
            // C/D layout: n = lane&31, m = (r&3)+8*(r>>2)+4*(lane>>5)
            #pragma unroll
            for (int r = 0; r < 16; ++r) {
                int m = (r & 3) + ((r >> 2) << 3) + ((lane >> 5) << 2);
                stage[sb][w][m][rho] = acc0[r] + acc1[r];
            }
        }
        __syncthreads();   // stage complete; next step uses stage[1-sb]

        if (w == 2 && s < T_STEPS)
            docell(0, sb, h0a + ((size_t)(s + 1) * NWG + blk) * CH,
                   &flags0[blk], (unsigned)(s + 1));
        if (w == 7 && s >= 1)
            docell(1, sb, h1a + ((size_t)s * NWG + blk) * CH,
                   &flags1[blk], (unsigned)s);
    }
}

// ---- epilogue FC: out[b][t][o] = sum_h h1[t][b][h]*fc_w[o][h] + fc_b[o] ----
__global__ __launch_bounds__(256) void fc_kern(
    const _Float16* __restrict__ h1a, const _Float16* __restrict__ fcwb,
    const float* __restrict__ fc_b, float* __restrict__ out)
{
    const int wv   = threadIdx.x >> 6;
    const int lane = threadIdx.x & 63;
    const int t    = blockIdx.x * 4 + wv;   // grid 128 -> t = 0..511
    const int kg   = (lane >> 5) << 3;
    // h1 slot t+1, chunk layout [wg][b][8u]
    const _Float16* ab = h1a + (((size_t)(t + 1) * NWG) + (kg >> 3)) * CH
                             + (size_t)(lane & 31) * UNITS;

    #pragma unroll 1
    for (int nt = 0; nt < 8; ++nt) {
        const _Float16* bb = fcwb + (size_t)(nt * 32 + (lane & 31)) * HID + kg;
        f32x16 acc0, acc1;
        #pragma unroll
        for (int r = 0; r < 16; ++r) { acc0[r] = 0.f; acc1[r] = 0.f; }
        #pragma unroll
        for (int kk = 0; kk < 64; kk += 2) {
            half8 a0 = *(const half8*)(ab + (size_t)kk * 2 * CH);
            half8 b0 = *(const half8*)(bb + kk * 16);
            acc0 = __builtin_amdgcn_mfma_f32_32x32x16_f16(a0, b0, acc0, 0, 0, 0);
            half8 a1 = *(const half8*)(ab + (size_t)(kk + 1) * 2 * CH);
            half8 b1 = *(const half8*)(bb + (kk + 1) * 16);
            acc1 = __builtin_amdgcn_mfma_f32_32x32x16_f16(a1, b1, acc1, 0, 0, 0);
        }
        const int o = nt * 32 + (lane & 31);
        const float bias = fc_b[o];
        #pragma unroll
        for (int r = 0; r < 16; ++r) {
            int m = (r & 3) + ((r >> 2) << 3) + ((lane >> 5) << 2);  // batch b
            out[(size_t)m * (T_STEPS * OUT_DIM) + (size_t)t * OUT_DIM + o]
                = acc0[r] + acc1[r] + bias;
        }
    }
}

// ---- pre-cast x (-> [t][chunk][b][8] fp16) and fc_w (-> fp16) ----
__global__ __launch_bounds__(256) void precast(
    const float* __restrict__ x, const float* __restrict__ fcw,
    _Float16* __restrict__ xb, _Float16* __restrict__ fcwb)
{
    const int idx = blockIdx.x * 256 + threadIdx.x;
    const int N1 = T_STEPS * BATCH * IN_DIM / 4;  // 1048576
    const int N2 = OUT_DIM * HID / 4;             // 65536
    if (idx < N1) {
        int e = idx << 2;
        int d = e & (IN_DIM - 1);
        int bt = e >> 8;
        int b = bt & 31;
        int t = bt >> 5;
        float4 v = *(const float4*)(x + ((size_t)b * T_STEPS + t) * IN_DIM + d);
        // dst: xb[((t*32 + d/8)*32 + b)*8 + d%8]
        _Float16* dst = xb + (((size_t)t * 32 + (d >> 3)) * 32 + b) * 8 + (d & 7);
        dst[0] = (_Float16)v.x; dst[1] = (_Float16)v.y;
        dst[2] = (_Float16)v.z; dst[3] = (_Float16)v.w;
    } else if (idx < N1 + N2) {
        int e = (idx - N1) << 2;
        float4 v = *(const float4*)(fcw + e);
        _Float16* dst = fcwb + e;
        dst[0] = (_Float16)v.x; dst[1] = (_Float16)v.y;
        dst[2] = (_Float16)v.z; dst[3] = (_Float16)v.w;
    }
}

extern "C" void kernel_launch(void* const* d_in, const int* in_sizes, int n_in,
                              void* d_out, int out_size, void* d_ws, size_t ws_size,
                              hipStream_t stream) {
    const float* x     = (const float*)d_in[0];
    const float* W_ih0 = (const float*)d_in[1];
    const float* W_hh0 = (const float*)d_in[2];
    const float* b_ih0 = (const float*)d_in[3];
    const float* b_hh0 = (const float*)d_in[4];
    const float* W_ih1 = (const float*)d_in[5];
    const float* W_hh1 = (const float*)d_in[6];
    const float* b_ih1 = (const float*)d_in[7];
    const float* b_hh1 = (const float*)d_in[8];
    const float* fc_w  = (const float*)d_in[9];
    const float* fc_b  = (const float*)d_in[10];
    float* out = (float*)d_out;

    char* ws = (char*)d_ws;
    unsigned* flags0 = (unsigned*)ws;            // 128 u32 dense
    unsigned* flags1 = (unsigned*)(ws + 512);    // 128 u32 dense
    size_t off = 4096;
    _Float16* xb   = (_Float16*)(ws + off); off += (size_t)T_STEPS * BATCH * IN_DIM * 2;
    _Float16* h0a  = (_Float16*)(ws + off); off += (size_t)(T_STEPS + 1) * NWG * CH * 2;
    _Float16* h1a  = (_Float16*)(ws + off); off += (size_t)(T_STEPS + 1) * NWG * CH * 2;
    _Float16* fcwb = (_Float16*)(ws + off); off += (size_t)OUT_DIM * HID * 2;
    // total ws use ~76 MB

    hipMemsetAsync(ws, 0, 4096, stream);                 // flags = 0
    hipMemsetAsync(h0a, 0, (size_t)NWG * CH * 2, stream); // h0 slot 0 = 0
    hipMemsetAsync(h1a, 0, (size_t)NWG * CH * 2, stream); // h1 slot 0 = 0
    precast<<<4352, 256, 0, stream>>>(x, fc_w, xb, fcwb);
    lstm_persist<<<NWG, TPB, 0, stream>>>(W_ih0, W_hh0, b_ih0, b_hh0,
                                          W_ih1, W_hh1, b_ih1, b_hh1,
                                          xb, h0a, h1a, flags0, flags1);
    fc_kern<<<128, 256, 0, stream>>>(h1a, fcwb, fc_b, out);
}

// Round 5
// 3878.120 us; speedup vs baseline: 1.8073x; 1.8073x over previous
//
#include <hip/hip_runtime.h>
#include <string.h>

// LSTM_13159779795583 : 2-layer LSTM (B=32,T=512,IN=256,H=1024) + FC(1024->256)
//
// Round 5: sentinel-in-data dataflow sync (no flags, no barriers).
//  - h slots pre-filled with fp16 NaN (0x7E7E via memsetAsync 0x7E); |h|<1 so
//    NaN is unreachable. Producers: one packed 8B WT store per lane,
//    fire-and-forget. Consumers of FRESH h (hh0, hh1 waves) load actual data
//    coherently (global_load_dwordx4 sc0 sc1) and retry 8B units still NaN.
//  - layer pipeline deepened: L1 at step s computes t=s-2, so xW1 waves read
//    h0 slot s-1 which this WG's hh0 waves verified at step s-1 -> plain
//    cacheable loads (write-once + first-touch-after-write = safe).
//  - h layout [slot][chunk=wg][batch][8u] (R4): 512B/producer, coalesced.
//  - one __syncthreads per step; stage dbuf; cells on x-waves 2 (L0), 7 (L1).

#define T_STEPS 512
#define BATCH   32
#define IN_DIM  256
#define HID     1024
#define OUT_DIM 256
#define NWG     128
#define TPB     512
#define UNITS   8               // hidden units per WG per layer
#define CH      (BATCH * UNITS) // fp16 per h-chunk (256 = 512B)
#define NSTEP   514             // s = 0..513 (L0: t=s, L1: t=s-2)

typedef _Float16 half8  __attribute__((ext_vector_type(8)));
typedef float    f32x16 __attribute__((ext_vector_type(16)));
typedef int      v4i    __attribute__((ext_vector_type(4)));

__device__ __forceinline__ float sigm(float x)      { return 1.f / (1.f + __expf(-x)); }
__device__ __forceinline__ float tanh_fast(float x) { return 2.f / (1.f + __expf(-2.f * x)) - 1.f; }

#define ATOMIC_ST8(p, v) __hip_atomic_store((p), (v), __ATOMIC_RELAXED, __HIP_MEMORY_SCOPE_AGENT)

// 8 coherent 16B loads (frag stride 1024B), one vmcnt(0). sc0 sc1 = bypass
// L1/L2 so freshly WT-stored remote data is visible.
__device__ __forceinline__ void ld8_coherent(const char* b0, v4i* F) {
    asm volatile(
        "global_load_dwordx4 %0, %8, off sc0 sc1\n\t"
        "global_load_dwordx4 %1, %8, off offset:1024 sc0 sc1\n\t"
        "global_load_dwordx4 %2, %8, off offset:2048 sc0 sc1\n\t"
        "global_load_dwordx4 %3, %8, off offset:3072 sc0 sc1\n\t"
        "global_load_dwordx4 %4, %9, off sc0 sc1\n\t"
        "global_load_dwordx4 %5, %9, off offset:1024 sc0 sc1\n\t"
        "global_load_dwordx4 %6, %9, off offset:2048 sc0 sc1\n\t"
        "global_load_dwordx4 %7, %9, off offset:3072 sc0 sc1\n\t"
        "s_waitcnt vmcnt(0)"
        : "=&v"(F[0]), "=&v"(F[1]), "=&v"(F[2]), "=&v"(F[3]),
          "=&v"(F[4]), "=&v"(F[5]), "=&v"(F[6]), "=&v"(F[7])
        : "v"(b0), "v"(b0 + 4096)
        : "memory");
}

// producer stores 8B units atomically; check low u16 of each 8B half
__device__ __forceinline__ bool frag_ok(v4i f) {
    return ((f.x & 0xffff) != 0x7E7E) & ((f.z & 0xffff) != 0x7E7E);
}

__global__ __launch_bounds__(TPB, 2) void lstm_persist(
    const float* __restrict__ W_ih0, const float* __restrict__ W_hh0,
    const float* __restrict__ b_ih0, const float* __restrict__ b_hh0,
    const float* __restrict__ W_ih1, const float* __restrict__ W_hh1,
    const float* __restrict__ b_ih1, const float* __restrict__ b_hh1,
    const _Float16* __restrict__ xb,
    _Float16* __restrict__ h0a, _Float16* __restrict__ h1a)
{
    __shared__ float stage[2][8][BATCH][33];  // double-buffered, padded
    __shared__ float cst[2][BATCH][UNITS];    // cell state, both layers
    __shared__ float biasS[2][32];            // b_ih + b_hh, this WG's rows

    const int tid  = threadIdx.x;
    const int w    = tid >> 6;        // wave id 0..7
    const int lane = tid & 63;
    const int rho  = lane & 31;       // MFMA A m-row (batch)
    const int kg   = (lane >> 5) << 3;// k sub-offset (0 or 8)
    const int blk  = blockIdx.x;

    // wave roles: matrix 0=W_hh0 1=W_ih0 2=W_ih1 3=W_hh1 ; K-range split
    const int matv[8]   = {0, 0,   1, 2, 2,   3, 3,   1};
    const int kbasev[8] = {0, 512, 0, 0, 512, 0, 512, 128};
    const int nkv[8]    = {32, 32, 8, 32, 32, 32, 32, 8};
    const int mat   = matv[w];
    const int kbase = kbasev[w];
    const int nk    = nkv[w];

    const float* wptr; int rowlen;
    if      (mat == 0) { wptr = W_hh0; rowlen = HID;    }
    else if (mat == 1) { wptr = W_ih0; rowlen = IN_DIM; }
    else if (mat == 2) { wptr = W_ih1; rowlen = HID;    }
    else               { wptr = W_hh1; rowlen = HID;    }

    // this lane's weight row: gate = rho>>3, unit = blk*8 + (rho&7)
    const int grow = (rho >> 3) * HID + blk * UNITS + (rho & 7);

    // ---- load + pack B fragments into registers (fp32 -> fp16), once ----
    half8 B[32];
    #pragma unroll
    for (int kk = 0; kk < 32; ++kk) {
        half8 bf;
        if (kk < nk) {
            const float* p = wptr + (size_t)grow * rowlen + kbase + kk * 16 + kg;
            float4 lo = *(const float4*)p;
            float4 hi = *(const float4*)(p + 4);
            bf[0] = (_Float16)lo.x; bf[1] = (_Float16)lo.y;
            bf[2] = (_Float16)lo.z; bf[3] = (_Float16)lo.w;
            bf[4] = (_Float16)hi.x; bf[5] = (_Float16)hi.y;
            bf[6] = (_Float16)hi.z; bf[7] = (_Float16)hi.w;
        } else {
            #pragma unroll
            for (int j = 0; j < 8; ++j) bf[j] = (_Float16)0.f;
        }
        B[kk] = bf;
    }

    // ---- init: biases, cell state ----
    if (tid < 64) {
        int L = tid >> 5, n = tid & 31;
        int gr = (n >> 3) * HID + blk * UNITS + (n & 7);
        biasS[L][n] = L ? (b_ih1[gr] + b_hh1[gr]) : (b_ih0[gr] + b_hh0[gr]);
    }
    ((float*)cst)[tid] = 0.f;  // 512 floats, one per thread
    __syncthreads();
    // (h slots: NaN-filled + slot0/slot1 zeroed by host-side memsets)

    // ---- cell helper: one wave handles one layer (4 units/lane) ----
    auto docell = [&](int L, int sb, _Float16* dst) {
        const int b  = lane >> 1;
        const int u0 = (lane & 1) * 4;
        _Float16 hh[4];
        #pragma unroll
        for (int j = 0; j < 4; ++j) {
            const int u = u0 + j;
            float pre[4];
            #pragma unroll
            for (int g = 0; g < 4; ++g) {
                const int n = g * 8 + u;
                float v = biasS[L][n];
                if (L == 0)
                    v += stage[sb][0][b][n] + stage[sb][1][b][n]
                       + stage[sb][2][b][n] + stage[sb][7][b][n];
                else
                    v += stage[sb][3][b][n] + stage[sb][4][b][n]
                       + stage[sb][5][b][n] + stage[sb][6][b][n];
                pre[g] = v;
            }
            float iv = sigm(pre[0]);
            float fv = sigm(pre[1]);
            float gv = tanh_fast(pre[2]);
            float ov = sigm(pre[3]);
            float c  = fv * cst[L][b][u] + iv * gv;
            cst[L][b][u] = c;
            hh[j] = (_Float16)(ov * tanh_fast(c));
        }
        unsigned long long pk;
        memcpy(&pk, hh, 8);
        // fire-and-forget WT store; consumers detect via non-NaN data
        ATOMIC_ST8((unsigned long long*)(dst + b * UNITS + u0), pk);
    };

    // ---- main loop: s=0..513; L0: t=s (s<512), L1: t=s-2 (s>=2) ----
    for (int s = 0; s < NSTEP; ++s) {
        const int  sb  = s & 1;
        const bool act = (mat <= 1) ? (s < T_STEPS) : (s >= 2);
        if (act) {
            const int cbase = (kbase >> 3) + (kg >> 3);
            f32x16 acc0, acc1;
            #pragma unroll
            for (int r = 0; r < 16; ++r) { acc0[r] = 0.f; acc1[r] = 0.f; }

            if (mat == 0 || mat == 3) {
                // fresh recurrent h: coherent retry loads, 4 groups of 8
                const _Float16* src = (mat == 0)
                    ? h0a + ((size_t)s * NWG + cbase) * CH
                    : h1a + ((size_t)(s - 1) * NWG + cbase) * CH;
                const char* base = (const char*)(src + rho * UNITS);
                #pragma unroll
                for (int g = 0; g < 4; ++g) {
                    v4i F[8];
                    ld8_coherent(base + g * 8192, F);
                    bool ok = frag_ok(F[0]) & frag_ok(F[1]) & frag_ok(F[2])
                            & frag_ok(F[3]) & frag_ok(F[4]) & frag_ok(F[5])
                            & frag_ok(F[6]) & frag_ok(F[7]);
                    while (!__all(ok)) {
                        __builtin_amdgcn_s_sleep(2);
                        ld8_coherent(base + g * 8192, F);
                        ok = frag_ok(F[0]) & frag_ok(F[1]) & frag_ok(F[2])
                           & frag_ok(F[3]) & frag_ok(F[4]) & frag_ok(F[5])
                           & frag_ok(F[6]) & frag_ok(F[7]);
                    }
                    #pragma unroll
                    for (int j = 0; j < 8; ++j) {
                        half8 a = __builtin_bit_cast(half8, F[j]);
                        if (j & 1) acc1 = __builtin_amdgcn_mfma_f32_32x32x16_f16(a, B[g * 8 + j], acc1, 0, 0, 0);
                        else       acc0 = __builtin_amdgcn_mfma_f32_32x32x16_f16(a, B[g * 8 + j], acc0, 0, 0, 0);
                    }
                }
            } else {
                // verified-or-static data: plain cacheable loads
                const _Float16* src = (mat == 1)
                    ? xb  + ((size_t)s * 32 + cbase) * CH
                    : h0a + ((size_t)(s - 1) * NWG + cbase) * CH;
                const _Float16* ap = src + rho * UNITS;
                #pragma unroll
                for (int kk = 0; kk < 32; kk += 2) {
                    if (kk < nk) {
                        half8 a = *(const half8*)(ap + (size_t)kk * 2 * CH);
                        acc0 = __builtin_amdgcn_mfma_f32_32x32x16_f16(a, B[kk], acc0, 0, 0, 0);
                    }
                    if (kk + 1 < nk) {
                        half8 a = *(const half8*)(ap + (size_t)(kk + 1) * 2 * CH);
                        acc1 = __builtin_amdgcn_mfma_f32_32x32x16_f16(a, B[kk + 1], acc1, 0, 0, 0);
                    }
                }
            }
            // C/D layout: n = lane&31, m = (r&3)+8*(r>>2)+4*(lane>>5)
            #pragma unroll
            for (int r = 0; r < 16; ++r) {
                int m = (r & 3) + ((r >> 2) << 3) + ((lane >> 5) << 2);
                stage[sb][w][m][rho] = acc0[r] + acc1[r];
            }
        }
        __syncthreads();   // stage complete; next step uses stage[1-sb]

        if (w == 2 && s < T_STEPS)  // L0 cell for t=s -> h0a slot s+1
            docell(0, sb, h0a + ((size_t)(s + 1) * NWG + blk) * CH);
        if (w == 7 && s >= 2)       // L1 cell for t=s-2 -> h1a slot s
            docell(1, sb, h1a + ((size_t)s * NWG + blk) * CH);
    }
}

// ---- epilogue FC: out[b][t][o] = sum_h h1[t][b][h]*fc_w[o][h] + fc_b[o] ----
// h1[t] lives in h1a slot t+2.
__global__ __launch_bounds__(256) void fc_kern(
    const _Float16* __restrict__ h1a, const _Float16* __restrict__ fcwb,
    const float* __restrict__ fc_b, float* __restrict__ out)
{
    const int wv   = threadIdx.x >> 6;
    const int lane = threadIdx.x & 63;
    const int t    = blockIdx.x * 4 + wv;   // grid 128 -> t = 0..511
    const int kg   = (lane >> 5) << 3;
    const _Float16* ab = h1a + (((size_t)(t + 2) * NWG) + (kg >> 3)) * CH
                             + (size_t)(lane & 31) * UNITS;

    #pragma unroll 1
    for (int nt = 0; nt < 8; ++nt) {
        const _Float16* bb = fcwb + (size_t)(nt * 32 + (lane & 31)) * HID + kg;
        f32x16 acc0, acc1;
        #pragma unroll
        for (int r = 0; r < 16; ++r) { acc0[r] = 0.f; acc1[r] = 0.f; }
        #pragma unroll
        for (int kk = 0; kk < 64; kk += 2) {
            half8 a0 = *(const half8*)(ab + (size_t)kk * 2 * CH);
            half8 b0 = *(const half8*)(bb + kk * 16);
            acc0 = __builtin_amdgcn_mfma_f32_32x32x16_f16(a0, b0, acc0, 0, 0, 0);
            half8 a1 = *(const half8*)(ab + (size_t)(kk + 1) * 2 * CH);
            half8 b1 = *(const half8*)(bb + (kk + 1) * 16);
            acc1 = __builtin_amdgcn_mfma_f32_32x32x16_f16(a1, b1, acc1, 0, 0, 0);
        }
        const int o = nt * 32 + (lane & 31);
        const float bias = fc_b[o];
        #pragma unroll
        for (int r = 0; r < 16; ++r) {
            int m = (r & 3) + ((r >> 2) << 3) + ((lane >> 5) << 2);  // batch b
            out[(size_t)m * (T_STEPS * OUT_DIM) + (size_t)t * OUT_DIM + o]
                = acc0[r] + acc1[r] + bias;
        }
    }
}

// ---- pre-cast x (-> [t][chunk][b][8] fp16) and fc_w (-> fp16) ----
__global__ __launch_bounds__(256) void precast(
    const float* __restrict__ x, const float* __restrict__ fcw,
    _Float16* __restrict__ xb, _Float16* __restrict__ fcwb)
{
    const int idx = blockIdx.x * 256 + threadIdx.x;
    const int N1 = T_STEPS * BATCH * IN_DIM / 4;  // 1048576
    const int N2 = OUT_DIM * HID / 4;             // 65536
    if (idx < N1) {
        int e = idx << 2;
        int d = e & (IN_DIM - 1);
        int bt = e >> 8;
        int b = bt & 31;
        int t = bt >> 5;
        float4 v = *(const float4*)(x + ((size_t)b * T_STEPS + t) * IN_DIM + d);
        _Float16* dst = xb + (((size_t)t * 32 + (d >> 3)) * 32 + b) * 8 + (d & 7);
        dst[0] = (_Float16)v.x; dst[1] = (_Float16)v.y;
        dst[2] = (_Float16)v.z; dst[3] = (_Float16)v.w;
    } else if (idx < N1 + N2) {
        int e = (idx - N1) << 2;
        float4 v = *(const float4*)(fcw + e);
        _Float16* dst = fcwb + e;
        dst[0] = (_Float16)v.x; dst[1] = (_Float16)v.y;
        dst[2] = (_Float16)v.z; dst[3] = (_Float16)v.w;
    }
}

extern "C" void kernel_launch(void* const* d_in, const int* in_sizes, int n_in,
                              void* d_out, int out_size, void* d_ws, size_t ws_size,
                              hipStream_t stream) {
    const float* x     = (const float*)d_in[0];
    const float* W_ih0 = (const float*)d_in[1];
    const float* W_hh0 = (const float*)d_in[2];
    const float* b_ih0 = (const float*)d_in[3];
    const float* b_hh0 = (const float*)d_in[4];
    const float* W_ih1 = (const float*)d_in[5];
    const float* W_hh1 = (const float*)d_in[6];
    const float* b_ih1 = (const float*)d_in[7];
    const float* b_hh1 = (const float*)d_in[8];
    const float* fc_w  = (const float*)d_in[9];
    const float* fc_b  = (const float*)d_in[10];
    float* out = (float*)d_out;

    const size_t SLOT = (size_t)NWG * CH;          // fp16 per slot (32768)
    char* ws = (char*)d_ws;
    size_t off = 0;
    _Float16* xb   = (_Float16*)(ws + off); off += (size_t)T_STEPS * BATCH * IN_DIM * 2;
    _Float16* h0a  = (_Float16*)(ws + off); off += (size_t)513 * SLOT * 2;
    _Float16* h1a  = (_Float16*)(ws + off); off += (size_t)515 * SLOT * 2;
    _Float16* fcwb = (_Float16*)(ws + off); off += (size_t)OUT_DIM * HID * 2;
    // total ws use ~76 MB

    // NaN-sentinel fill (0x7E7E = fp16 NaN), then zero the initial-state slots
    hipMemsetAsync(h0a, 0x7E, 513 * SLOT * 2, stream);
    hipMemsetAsync(h1a, 0x7E, 515 * SLOT * 2, stream);
    hipMemsetAsync(h0a, 0, SLOT * 2, stream);            // h0 slot 0 = h0[-1] = 0
    hipMemsetAsync(h1a + SLOT, 0, SLOT * 2, stream);     // h1 slot 1 = h1[-1] = 0
    precast<<<4352, 256, 0, stream>>>(x, fc_w, xb, fcwb);
    lstm_persist<<<NWG, TPB, 0, stream>>>(W_ih0, W_hh0, b_ih0, b_hh0,
                                          W_ih1, W_hh1, b_ih1, b_hh1,
                                          xb, h0a, h1a);
    fc_kern<<<128, 256, 0, stream>>>(h1a, fcwb, fc_b, out);
}